// Round 11
// baseline (242.570 us; speedup 1.0000x reference)
//
#include <hip/hip_runtime.h>
#include <math.h>

#define NEG_SLOPE 0.2f

typedef __attribute__((ext_vector_type(8))) short bf16x8;
typedef __attribute__((ext_vector_type(4))) float f32x4;

// float -> bf16 bits, round-to-nearest-even
__device__ __forceinline__ unsigned short f2bf(float f) {
    unsigned u = __float_as_uint(f);
    unsigned r = (u + 0x7FFFu + ((u >> 16) & 1u)) >> 16;
    return (unsigned short)r;
}

// unpack uint4 (8 bf16) -> accumulate a[0..7] += x * h[k]
__device__ __forceinline__ void acc8(float* a, uint4 u, float x) {
    a[0] += x * __uint_as_float(u.x << 16);
    a[1] += x * __uint_as_float(u.x & 0xFFFF0000u);
    a[2] += x * __uint_as_float(u.y << 16);
    a[3] += x * __uint_as_float(u.y & 0xFFFF0000u);
    a[4] += x * __uint_as_float(u.z << 16);
    a[5] += x * __uint_as_float(u.z & 0xFFFF0000u);
    a[6] += x * __uint_as_float(u.w << 16);
    a[7] += x * __uint_as_float(u.w & 0xFFFF0000u);
}

__device__ __forceinline__ unsigned pack2(unsigned short lo, unsigned short hi) {
    return (unsigned)lo | ((unsigned)hi << 16);
}

// ---------------- K_PRE: {deg histogram (2 edges/thr) | wvec | wconv} ----------------
__global__ __launch_bounds__(256) void k_pre(
    const int* __restrict__ dst, int* __restrict__ deg, int E, int nbDeg,
    const float* __restrict__ Wd, const float* __restrict__ ad,
    const float* __restrict__ Ws, const float* __restrict__ as_,
    float* __restrict__ wdst, float* __restrict__ wsrc,
    const float* __restrict__ Wlin, unsigned short* __restrict__ Wb) {
    int b = blockIdx.x, t = threadIdx.x;
    if (b < nbDeg) {
        int i = (b * 256 + t) * 2;
        if (i < E) {
            int2 dp = *(const int2*)(dst + i);
            atomicAdd(&deg[dp.x], 1);
            if (i + 1 < E) atomicAdd(&deg[dp.y], 1);
        }
    } else if (b == nbDeg) {
        // wdst[d] = sum_h W_dst[d,h]*a_dst[h]; wsrc[d] = sum_h W_src[d,h]*a_src[h]
        const float* W = (t < 128) ? Wd : Ws;
        const float* a = (t < 128) ? ad : as_;
        int d = t & 127;
        float s = 0.f;
        #pragma unroll 8
        for (int h = 0; h < 128; ++h) s += W[d * 128 + h] * a[h];
        if (t < 128) wdst[d] = s; else wsrc[d] = s;
    } else {
        // Wb[col][k] = bf16(W_lin[k][col])
        int idx = (b - nbDeg - 1) * 256 + t;
        int col = idx >> 7, k = idx & 127;
        Wb[idx] = f2bf(Wlin[k * 64 + col]);
    }
}

// ---------------- role helpers for K_MID ----------------
// 32 rows/block, 8 rows/wave: 4 independent load+reduce chains per wave (ILP).
__device__ __forceinline__ void rowdot_role(const float* __restrict__ X,
                                            const float* __restrict__ v,
                                            float* __restrict__ out, int n,
                                            int vb, int t) {
    int wave = t >> 6, lane = t & 63;
    int half = lane >> 5, li = lane & 31;
    int row0 = (vb * 4 + wave) * 8 + half;     // rows row0 + 2*{0,1,2,3}
    const float4* X4 = (const float4*)X;
    const float4* V4 = (const float4*)v;
    float4 bv = V4[li];
    float p[4];
    #pragma unroll
    for (int k = 0; k < 4; ++k) {
        int row = row0 + 2 * k;
        p[k] = 0.f;
        if (row < n) {
            float4 x = X4[(size_t)row * 32 + li];
            p[k] = x.x * bv.x + x.y * bv.y + x.z * bv.z + x.w * bv.w;
        }
    }
    #pragma unroll
    for (int off = 16; off; off >>= 1) {
        #pragma unroll
        for (int k = 0; k < 4; ++k) p[k] += __shfl_xor(p[k], off);
    }
    if (li == 0) {
        #pragma unroll
        for (int k = 0; k < 4; ++k) {
            int row = row0 + 2 * k;
            if (row < n) out[row] = p[k];
        }
    }
}

__device__ __forceinline__ void hsrc_role(const float* __restrict__ X,
                                          const float* __restrict__ W,
                                          unsigned short* __restrict__ Hb,
                                          int nrows, int row0, int t,
                                          float* __restrict__ Xs /*32*128 lds*/) {
    #pragma unroll
    for (int i = 0; i < 16; ++i) {
        int idx = t + i * 256;
        int r = idx >> 7;
        Xs[r * 128 + (idx & 127)] = (row0 + r < nrows) ? X[(size_t)row0 * 128 + idx] : 0.f;
    }
    __syncthreads();
    int cg = t & 31, rg = t >> 5;
    float acc[4][4];
    #pragma unroll
    for (int i = 0; i < 4; ++i)
        #pragma unroll
        for (int j = 0; j < 4; ++j) acc[i][j] = 0.f;
    const float4* W4 = (const float4*)W;
    #pragma unroll 4
    for (int d = 0; d < 128; ++d) {
        float4 wv = W4[d * 32 + cg];
        float x0 = Xs[(rg * 4 + 0) * 128 + d], x1 = Xs[(rg * 4 + 1) * 128 + d];
        float x2 = Xs[(rg * 4 + 2) * 128 + d], x3 = Xs[(rg * 4 + 3) * 128 + d];
        acc[0][0] += x0 * wv.x; acc[0][1] += x0 * wv.y; acc[0][2] += x0 * wv.z; acc[0][3] += x0 * wv.w;
        acc[1][0] += x1 * wv.x; acc[1][1] += x1 * wv.y; acc[1][2] += x1 * wv.z; acc[1][3] += x1 * wv.w;
        acc[2][0] += x2 * wv.x; acc[2][1] += x2 * wv.y; acc[2][2] += x2 * wv.z; acc[2][3] += x2 * wv.w;
        acc[3][0] += x3 * wv.x; acc[3][1] += x3 * wv.y; acc[3][2] += x3 * wv.z; acc[3][3] += x3 * wv.w;
    }
    #pragma unroll
    for (int i = 0; i < 4; ++i) {
        int gr = row0 + rg * 4 + i;
        if (gr < nrows) {
            ushort4 o;
            o.x = f2bf(acc[i][0]); o.y = f2bf(acc[i][1]);
            o.z = f2bf(acc[i][2]); o.w = f2bf(acc[i][3]);
            *(ushort4*)&Hb[(size_t)gr * 128 + cg * 4] = o;
        }
    }
}

// Fused scan role: block vb handles deg[vb*1024 .. vb*1024+1024) -> rowptr.
// Offset via redundant sum of deg[0..vb*1024) (L2-resident, G16-safe).
__device__ __forceinline__ void scan_role(const int* __restrict__ deg,
                                          int* __restrict__ rowptr, int n, int E,
                                          int vb, int t, int* __restrict__ sd) {
    const int4* deg4 = (const int4*)deg;
    int nq = vb * 256;
    int s = 0;
    for (int i = t; i < nq; i += 256) {
        int4 v = deg4[i];
        s += (v.x + v.y) + (v.z + v.w);
    }
    sd[t] = s;
    __syncthreads();
    for (int off = 128; off; off >>= 1) {
        if (t < off) sd[t] += sd[t + off];
        __syncthreads();
    }
    int offset = sd[0];
    __syncthreads();
    int base = vb * 1024 + t * 4;
    int d[4]; int tsum = 0;
    #pragma unroll
    for (int i = 0; i < 4; ++i) { d[i] = (base + i < n) ? deg[base + i] : 0; tsum += d[i]; }
    sd[t] = tsum;
    __syncthreads();
    for (int off = 1; off < 256; off <<= 1) {
        int v = (t >= off) ? sd[t - off] : 0;
        __syncthreads();
        sd[t] += v;
        __syncthreads();
    }
    int excl = sd[t] - tsum + offset;
    #pragma unroll
    for (int i = 0; i < 4; ++i) {
        if (base + i < n) rowptr[base + i] = excl;
        excl += d[i];
    }
    if (vb == 0 && t == 0) rowptr[n] = E;
}

// ---------------- K_MID: {hsrc | rowdot(xL) | rowdot(xA) | full scan} ----------------
__global__ __launch_bounds__(256) void k_mid(
    const int* __restrict__ deg, int* __restrict__ rowptr, int nScan, int n, int E,
    const float* __restrict__ xL, const float* __restrict__ wdst,
    float* __restrict__ sdst, int nRL, int NL,
    const float* __restrict__ xA, const float* __restrict__ wsrc,
    float* __restrict__ ssrc, int nRA, int NA,
    const float* __restrict__ Wsrc, unsigned short* __restrict__ Hb, int nH) {
    __shared__ float smemf[32 * 128];
    int b = blockIdx.x, t = threadIdx.x;
    if (b < nH) {
        hsrc_role(xA, Wsrc, Hb, NA, b * 32, t, smemf);
    } else if (b < nH + nRL) {
        rowdot_role(xL, wdst, sdst, NL, b - nH, t);
    } else if (b < nH + nRL + nRA) {
        rowdot_role(xA, wsrc, ssrc, NA, b - nH - nRL, t);
    } else {
        scan_role(deg, rowptr, n, E, b - nH - nRL - nRA, t, (int*)smemf);
    }
}

// ---------------- K_SCATTER: 2 edges/thread; ex = exp(leaky(e)); CSR slot ----------------
__global__ void k_scatter(const int* __restrict__ src, const int* __restrict__ dst,
                          const float* __restrict__ ssrc, const float* __restrict__ sdst,
                          const int* __restrict__ rowptr, int* __restrict__ cursor,
                          int2* __restrict__ csr_pair, int E) {
    int i = (blockIdx.x * blockDim.x + threadIdx.x) * 2;
    if (i >= E) return;
    int2 sp = *(const int2*)(src + i);
    int2 dp = *(const int2*)(dst + i);
    bool v1 = (i + 1 < E);
    float e0 = ssrc[sp.x] + sdst[dp.x];
    float e1 = v1 ? ssrc[sp.y] + sdst[dp.y] : 0.f;
    e0 = e0 > 0.f ? e0 : NEG_SLOPE * e0;
    e1 = e1 > 0.f ? e1 : NEG_SLOPE * e1;
    float x0 = __expf(e0), x1 = __expf(e1);
    int pos0 = rowptr[dp.x] + atomicAdd(&cursor[dp.x], 1);
    csr_pair[pos0] = make_int2(sp.x, __float_as_int(x0));
    if (v1) {
        int pos1 = rowptr[dp.y] + atomicAdd(&cursor[dp.y], 1);
        csr_pair[pos1] = make_int2(sp.y, __float_as_int(x1));
    }
}

// ---------------- K_GATOUT: 1 wave / 16 rows; interleaved 4-row gather -> LDS -> MFMA ----------------
// Phase 1: lane-group grp owns rows {grp, 4+grp, 8+grp, 12+grp}; per iteration
// issues 2 edges x 4 rows = 8 independent pair+gather chains (cndmask'd addrs,
// x=0 for invalid). Phase 2: this wave MFMAs its own 16 rows x 64 cols (K=128).
__global__ __launch_bounds__(64) void k_gatout(
    const int* __restrict__ rowptr, const int2* __restrict__ csr_pair,
    const unsigned short* __restrict__ Hb, const float* __restrict__ b_al,
    const unsigned short* __restrict__ Wb, const float* __restrict__ b_lin,
    float* __restrict__ out, int n) {
    __shared__ unsigned short Gs[16 * 128];   // 4 KB, 16B slots XOR-swizzled
    int lane = threadIdx.x & 63;
    int grp = lane >> 4, gl = lane & 15;
    const uint4* H16 = (const uint4*)Hb;
    int row0b = blockIdx.x * 16;
    const float4* B4 = (const float4*)b_al;
    float4 bA = B4[gl * 2], bB = B4[gl * 2 + 1];

    int jj[4], ee[4];
    float acc[4][8];
    float den[4];
    #pragma unroll
    for (int r = 0; r < 4; ++r) {
        int row = row0b + r * 4 + grp;
        if (row < n) { jj[r] = rowptr[row]; ee[r] = rowptr[row + 1]; }
        else         { jj[r] = 0;           ee[r] = 0; }
        den[r] = 0.f;
        #pragma unroll
        for (int k = 0; k < 8; ++k) acc[r][k] = 0.f;
    }

    while (jj[0] < ee[0] || jj[1] < ee[1] || jj[2] < ee[2] || jj[3] < ee[3]) {
        #pragma unroll
        for (int r = 0; r < 4; ++r) {
            bool v0 = jj[r] < ee[r];
            bool v1 = jj[r] + 1 < ee[r];
            int j0 = v0 ? jj[r] : 0;
            int j1 = v1 ? jj[r] + 1 : 0;
            int2 p0 = csr_pair[j0];
            int2 p1 = csr_pair[j1];
            uint4 u0 = H16[(size_t)p0.x * 16 + gl];
            uint4 u1 = H16[(size_t)p1.x * 16 + gl];
            float x0 = v0 ? __int_as_float(p0.y) : 0.f;
            float x1 = v1 ? __int_as_float(p1.y) : 0.f;
            den[r] += x0 + x1;
            acc8(acc[r], u0, x0);
            acc8(acc[r], u1, x1);
            jj[r] += 2;
        }
    }

    #pragma unroll
    for (int r = 0; r < 4; ++r) {
        int rl = r * 4 + grp;
        float inv = den[r] > 0.f ? 1.f / den[r] : 0.f;
        unsigned short g0 = f2bf(fmaxf(acc[r][0] * inv + bA.x, 0.f));
        unsigned short g1 = f2bf(fmaxf(acc[r][1] * inv + bA.y, 0.f));
        unsigned short g2 = f2bf(fmaxf(acc[r][2] * inv + bA.z, 0.f));
        unsigned short g3 = f2bf(fmaxf(acc[r][3] * inv + bA.w, 0.f));
        unsigned short g4 = f2bf(fmaxf(acc[r][4] * inv + bB.x, 0.f));
        unsigned short g5 = f2bf(fmaxf(acc[r][5] * inv + bB.y, 0.f));
        unsigned short g6 = f2bf(fmaxf(acc[r][6] * inv + bB.z, 0.f));
        unsigned short g7 = f2bf(fmaxf(acc[r][7] * inv + bB.w, 0.f));
        uint4 gpack = make_uint4(pack2(g0, g1), pack2(g2, g3), pack2(g4, g5), pack2(g6, g7));
        int slot = gl ^ rl;                    // swizzle (rl in 0..15)
        *(uint4*)&Gs[rl * 128 + slot * 8] = gpack;
    }
    __syncthreads();

    // phase 2: MFMA. A: m=lane&15, k-chunk ci=s*4+kq; B: n=lane&15;
    // D: col=lane&15, row=(lane>>4)*4+reg (m89-verified layouts).
    int m = lane & 15, kq = lane >> 4;
    f32x4 acc0 = {0.f, 0.f, 0.f, 0.f};
    f32x4 acc1 = {0.f, 0.f, 0.f, 0.f};
    f32x4 acc2 = {0.f, 0.f, 0.f, 0.f};
    f32x4 acc3 = {0.f, 0.f, 0.f, 0.f};
    const bf16x8* B0 = (const bf16x8*)(Wb + (size_t)(0 * 16 + m) * 128);
    const bf16x8* B1 = (const bf16x8*)(Wb + (size_t)(1 * 16 + m) * 128);
    const bf16x8* B2 = (const bf16x8*)(Wb + (size_t)(2 * 16 + m) * 128);
    const bf16x8* B3 = (const bf16x8*)(Wb + (size_t)(3 * 16 + m) * 128);
    #pragma unroll
    for (int s = 0; s < 4; ++s) {
        int ci = s * 4 + kq;
        int slot = ci ^ m;
        bf16x8 a = *(const bf16x8*)&Gs[m * 128 + slot * 8];
        acc0 = __builtin_amdgcn_mfma_f32_16x16x32_bf16(a, B0[ci], acc0, 0, 0, 0);
        acc1 = __builtin_amdgcn_mfma_f32_16x16x32_bf16(a, B1[ci], acc1, 0, 0, 0);
        acc2 = __builtin_amdgcn_mfma_f32_16x16x32_bf16(a, B2[ci], acc2, 0, 0, 0);
        acc3 = __builtin_amdgcn_mfma_f32_16x16x32_bf16(a, B3[ci], acc3, 0, 0, 0);
    }
    float bl0 = b_lin[0 * 16 + m], bl1 = b_lin[1 * 16 + m];
    float bl2 = b_lin[2 * 16 + m], bl3 = b_lin[3 * 16 + m];
    #pragma unroll
    for (int j = 0; j < 4; ++j) {
        int row = row0b + kq * 4 + j;
        if (row < n) {
            float* orow = out + (size_t)row * 64;
            orow[0 * 16 + m] = acc0[j] + bl0;
            orow[1 * 16 + m] = acc1[j] + bl1;
            orow[2 * 16 + m] = acc2[j] + bl2;
            orow[3 * 16 + m] = acc3[j] + bl3;
        }
    }
}

extern "C" void kernel_launch(void* const* d_in, const int* in_sizes, int n_in,
                              void* d_out, int out_size, void* d_ws, size_t ws_size,
                              hipStream_t stream) {
    const float* x_label  = (const float*)d_in[0];
    const float* x_attr   = (const float*)d_in[1];
    const float* W_src_al = (const float*)d_in[7];
    const float* W_dst_al = (const float*)d_in[8];
    const float* a_src_al = (const float*)d_in[9];
    const float* a_dst_al = (const float*)d_in[10];
    const float* b_al     = (const float*)d_in[11];
    const float* W_lin    = (const float*)d_in[12];
    const float* b_lin    = (const float*)d_in[13];
    const int* edge_src   = (const int*)d_in[16];
    const int* edge_dst   = (const int*)d_in[17];

    const int D = 128;
    const int N_L = in_sizes[0] / D;
    const int N_A = in_sizes[1] / D;
    const int E   = in_sizes[16];

    const int nbDeg = (E + 511) / 512;          // 2 edges/thread
    const int nScan = (N_L + 1023) / 1024;
    const int nRL   = (N_L + 31) / 32;
    const int nRA   = (N_A + 31) / 32;
    const int nH    = (N_A + 31) / 32;

    // workspace layout (16B-aligned blocks)
    float* ws = (float*)d_ws;
    float* s_src = ws;                                  // N_A f
    float* s_dst = s_src + N_A;                         // N_L f
    float* wdst  = s_dst + N_L;                         // 128 f
    float* wsrc  = wdst + 128;                          // 128 f
    int*   deg    = (int*)(wsrc + 128);                 // N_L i   -- zeroed
    int*   cursor = deg + N_L;                          // N_L i   -- zeroed
    int*   rowptr = cursor + N_L;                       // N_L+4 i
    int2*  csr_pair = (int2*)(rowptr + N_L + 4);        // E int2 (offset even)
    unsigned short* Hb = (unsigned short*)(csr_pair + E);   // N_A*128 bf16
    unsigned short* Wb = Hb + (size_t)N_A * 128;            // 64*128 bf16

    float* out = (float*)d_out;

    // zero deg + cursor
    hipMemsetAsync(deg, 0, (size_t)2 * N_L * sizeof(int), stream);

    // K1: deg histogram | weight-vector projections | W_lin -> bf16^T
    k_pre<<<nbDeg + 1 + 32, 256, 0, stream>>>(edge_dst, deg, E, nbDeg,
                                              W_dst_al, a_dst_al, W_src_al, a_src_al,
                                              wdst, wsrc, W_lin, Wb);
    // K2: hsrc GEMM | s_dst | s_src | full rowptr scan
    k_mid<<<nH + nRL + nRA + nScan, 256, 0, stream>>>(
        deg, rowptr, nScan, N_L, E,
        x_label, wdst, s_dst, nRL, N_L,
        x_attr, wsrc, s_src, nRA, N_A,
        W_src_al, Hb, nH);
    // K3: edge scatter into CSR with precomputed exp (2 edges/thread)
    k_scatter<<<(E + 511) / 512, 256, 0, stream>>>(edge_src, edge_dst, s_src, s_dst,
                                                   rowptr, cursor, csr_pair, E);
    // K4: fused gather + softmax-normalize + bias + relu + MFMA epilogue
    k_gatout<<<(N_L + 15) / 16, 64, 0, stream>>>(rowptr, csr_pair, Hb, b_al,
                                                 Wb, b_lin, out, N_L);
}